// Round 1
// baseline (404.229 us; speedup 1.0000x reference)
//
#include <hip/hip_runtime.h>
#include <math.h>

#define BATCH 512
#define DIM 512
#define NCLASS 100000
#define BN 64
#define NBLK ((NCLASS + BN - 1) / BN) /* 1563 */
#define S_SCALE 30.0f
#define COSM 0.8775825618903728f
#define SINM 0.4794255386042030f

typedef unsigned short u16;
typedef __attribute__((ext_vector_type(8))) short short8;
typedef __attribute__((ext_vector_type(4))) float floatx4;

// ws layout (bytes):
//   [0, 524288)            xn bf16 [512][512]
//   [524288, 526336)       tlogit float[512]
//   [526336, 528384)       nll    float[512]
//   [528384, +NBLK*512*4)  partials [NBLK][512]   (~3.2 MB; total ~3.7 MB)

__device__ __forceinline__ u16 f2bf(float f) {
    union { float f; unsigned int u; } v;
    v.f = f;
    unsigned int u = v.u;
    u += 0x7fffu + ((u >> 16) & 1u);   // round-to-nearest-even
    return (u16)(u >> 16);
}

// ---------------- Kernel 1: normalize x rows -> bf16 ----------------
__global__ void xnorm_kernel(const float* __restrict__ x, u16* __restrict__ xn) {
    const int row = blockIdx.x;
    const int t = threadIdx.x; // 64 threads = 1 wave
    const floatx4* xr = (const floatx4*)(x + (size_t)row * DIM);
    floatx4 a = xr[t];
    floatx4 b = xr[t + 64];
    float ss = a[0]*a[0] + a[1]*a[1] + a[2]*a[2] + a[3]*a[3]
             + b[0]*b[0] + b[1]*b[1] + b[2]*b[2] + b[3]*b[3];
#pragma unroll
    for (int d = 1; d < 64; d <<= 1) ss += __shfl_xor(ss, d);
    const float rn = 1.0f / fmaxf(sqrtf(ss), 1e-12f);
    ushort4 ua, ub;
    ua.x = f2bf(a[0]*rn); ua.y = f2bf(a[1]*rn); ua.z = f2bf(a[2]*rn); ua.w = f2bf(a[3]*rn);
    ub.x = f2bf(b[0]*rn); ub.y = f2bf(b[1]*rn); ub.z = f2bf(b[2]*rn); ub.w = f2bf(b[3]*rn);
    u16* orow = xn + (size_t)row * DIM;
    *(ushort4*)(orow + 4*t)       = ua;
    *(ushort4*)(orow + 256 + 4*t) = ub;
}

// ---------------- Kernel 2: main fused GEMM + partial softmax ----------------
// Block: 512 threads (8 waves). Classes [c0, c0+64). Full batch M=512.
// LDS: normalized-w bf16 tile [64][512], XOR-swizzled in 16B granules (64 KB).
__global__ void arcface_main(const float* __restrict__ w,
                             const u16* __restrict__ xn,
                             const int* __restrict__ target,
                             float* __restrict__ partials,
                             float* __restrict__ tlogit) {
    __shared__ u16 wb[BN * DIM]; // 65536 B

    const int c0 = blockIdx.x * BN;
    const int t = threadIdx.x;

    // ---- Phase A: stage normalized w tile (fp32 -> bf16) into LDS ----
    {
        const int r = t >> 3;        // local class row 0..63
        const int q = t & 7;         // 8 threads per row
        const int cg = c0 + r;
        floatx4 v[16];
        float ss = 0.f;
        if (cg < NCLASS) {
            const floatx4* wr = (const floatx4*)(w + (size_t)cg * DIM);
#pragma unroll
            for (int i = 0; i < 16; ++i) {
                v[i] = wr[q + (i << 3)];
                ss += v[i][0]*v[i][0] + v[i][1]*v[i][1] + v[i][2]*v[i][2] + v[i][3]*v[i][3];
            }
        } else {
#pragma unroll
            for (int i = 0; i < 16; ++i) { v[i][0]=0.f; v[i][1]=0.f; v[i][2]=0.f; v[i][3]=0.f; }
        }
        // reduce across the 8 threads of this row (lane bits 0..2)
        ss += __shfl_xor(ss, 1);
        ss += __shfl_xor(ss, 2);
        ss += __shfl_xor(ss, 4);
        const float rs = 1.0f / fmaxf(sqrtf(ss), 1e-12f);
#pragma unroll
        for (int i = 0; i < 16; ++i) {
            const int col4 = q + (i << 3);               // float4 index within row
            const int gp = (col4 >> 1) ^ (r & 7);        // swizzled 16B granule
            const int off = r * DIM + gp * 8 + (col4 & 1) * 4;
            ushort4 u;
            u.x = f2bf(v[i][0] * rs); u.y = f2bf(v[i][1] * rs);
            u.z = f2bf(v[i][2] * rs); u.w = f2bf(v[i][3] * rs);
            *(ushort4*)(&wb[off]) = u;
        }
    }
    __syncthreads();

    // ---- Phase B: MFMA K-loop ----
    const int wave = t >> 6;      // 0..7 -> m range [wave*64, +64)
    const int lane = t & 63;
    const int quad = lane >> 4;   // 0..3
    const int nin  = lane & 15;   // 0..15
    const int mbase = wave * 64;

    floatx4 acc[4][4];
#pragma unroll
    for (int mi = 0; mi < 4; ++mi)
#pragma unroll
        for (int ni = 0; ni < 4; ++ni) {
            acc[mi][ni][0] = 0.f; acc[mi][ni][1] = 0.f;
            acc[mi][ni][2] = 0.f; acc[mi][ni][3] = 0.f;
        }

    for (int kk = 0; kk < 16; ++kk) {
        short8 a[4], b[4];
        const int k = kk * 32 + quad * 8;
#pragma unroll
        for (int mi = 0; mi < 4; ++mi) {
            const int m = mbase + mi * 16 + nin;   // A[m=lane&15][k=quad*8+j]
            a[mi] = *(const short8*)(xn + (size_t)m * DIM + k);
        }
#pragma unroll
        for (int ni = 0; ni < 4; ++ni) {
            const int cl = ni * 16 + nin;          // B: fixed n = lane&15, 8 contiguous k
            const int gp = ((kk << 2) + quad) ^ (cl & 7);
            b[ni] = *(const short8*)(&wb[cl * DIM + gp * 8]);
        }
#pragma unroll
        for (int mi = 0; mi < 4; ++mi)
#pragma unroll
            for (int ni = 0; ni < 4; ++ni)
                acc[mi][ni] = __builtin_amdgcn_mfma_f32_16x16x32_bf16(
                    a[mi], b[ni], acc[mi][ni], 0, 0, 0);
    }

    // ---- Phase C: epilogue — arcface transform + per-row exp-sum ----
    // C/D layout: col(n) = lane&15, row(m) = (lane>>4)*4 + reg
#pragma unroll
    for (int mi = 0; mi < 4; ++mi) {
#pragma unroll
        for (int reg = 0; reg < 4; ++reg) {
            const int m = mbase + mi * 16 + quad * 4 + reg;
            const int tg = target[m];
            float psum = 0.f;
#pragma unroll
            for (int ni = 0; ni < 4; ++ni) {
                const int c = c0 + ni * 16 + nin;
                if (c < NCLASS) {
                    const float cosv = acc[mi][ni][reg];
                    float lg;
                    if (c == tg) {
                        const float sine = sqrtf(fmaxf(1.f - cosv * cosv, 0.f));
                        float phi = cosv * COSM - sine * SINM;
                        if (!(cosv > 0.f)) phi = cosv;   // easy_margin
                        lg = S_SCALE * phi;
                        tlogit[m] = lg;
                    } else {
                        lg = S_SCALE * cosv;
                    }
                    psum += __expf(lg - S_SCALE);        // fixed shift S (logit <= S)
                }
            }
            // reduce over the 16 n-lanes (lane bits 0..3)
            psum += __shfl_xor(psum, 1);
            psum += __shfl_xor(psum, 2);
            psum += __shfl_xor(psum, 4);
            psum += __shfl_xor(psum, 8);
            if (nin == 0)
                partials[(size_t)blockIdx.x * BATCH + m] = psum;
        }
    }
}

// ---------------- Kernel 3a: per-row logsumexp + nll ----------------
__global__ void reduce_lse(const float* __restrict__ partials,
                           const float* __restrict__ tlogit,
                           float* __restrict__ nll) {
    const int m = blockIdx.x;
    const int t = threadIdx.x; // 256
    float s = 0.f;
    for (int b = t; b < NBLK; b += 256) s += partials[(size_t)b * BATCH + m];
#pragma unroll
    for (int d = 1; d < 64; d <<= 1) s += __shfl_xor(s, d);
    __shared__ float red[4];
    if ((t & 63) == 0) red[t >> 6] = s;
    __syncthreads();
    if (t == 0) {
        const float tot = red[0] + red[1] + red[2] + red[3];
        nll[m] = (logf(tot) + S_SCALE) - tlogit[m];
    }
}

// ---------------- Kernel 3b: mean ----------------
__global__ void reduce_mean(const float* __restrict__ nll, float* __restrict__ out) {
    const int t = threadIdx.x; // 512
    float s = nll[t];
#pragma unroll
    for (int d = 1; d < 64; d <<= 1) s += __shfl_xor(s, d);
    __shared__ float red[8];
    if ((t & 63) == 0) red[t >> 6] = s;
    __syncthreads();
    if (t == 0) {
        float tot = 0.f;
#pragma unroll
        for (int i = 0; i < 8; ++i) tot += red[i];
        out[0] = tot / (float)BATCH;
    }
}

extern "C" void kernel_launch(void* const* d_in, const int* in_sizes, int n_in,
                              void* d_out, int out_size, void* d_ws, size_t ws_size,
                              hipStream_t stream) {
    const float* x = (const float*)d_in[0];
    const float* w = (const float*)d_in[1];
    const int* target = (const int*)d_in[2];

    char* ws = (char*)d_ws;
    u16* xn        = (u16*)ws;
    float* tlogit  = (float*)(ws + 524288);
    float* nll     = (float*)(ws + 526336);
    float* partials= (float*)(ws + 528384);

    xnorm_kernel<<<BATCH, 64, 0, stream>>>(x, xn);
    arcface_main<<<NBLK, 512, 0, stream>>>(w, xn, target, partials, tlogit);
    reduce_lse<<<BATCH, 256, 0, stream>>>(partials, tlogit, nll);
    reduce_mean<<<1, 512, 0, stream>>>(nll, (float*)d_out);
}